// Round 6
// baseline (418.260 us; speedup 1.0000x reference)
//
#include <hip/hip_runtime.h>
#include <hip/hip_bf16.h>
#include <math.h>

#define Bn   8
#define DIM  128
#define Hs   64
#define Ws   64
#define PADn 3
#define GC   16
#define Gn   8
#define CMID 32    // DIM/RED
#define NW   392   // K*K*G
#define NWP  416   // w2b padded rows

typedef __bf16 bf16x8 __attribute__((ext_vector_type(8)));
typedef float  f32x4  __attribute__((ext_vector_type(4)));
typedef _Float16 h2v  __attribute__((ext_vector_type(2)));

__device__ __forceinline__ f32x4 mfma16(bf16x8 a, bf16x8 b, f32x4 c) {
    return __builtin_amdgcn_mfma_f32_16x16x32_bf16(a, b, c, 0, 0, 0);
}

__device__ __forceinline__ __bf16 tobf(float v) {
    __hip_bfloat16 h = __float2bfloat16(v);
    return *reinterpret_cast<__bf16*>(&h);
}

__device__ __forceinline__ unsigned su16(float f) {
    __hip_bfloat16 h = __float2bfloat16(f);
    return (unsigned)*reinterpret_cast<unsigned short*>(&h);
}

// ---------------- K0: convert weights to bf16 (+ permute pw1 K-dim) ----------------
// y is written permuted: y_p[pix][j] = y[pix][c(j)], c(j) = g*16 + q + 4m,
// q=j>>5, g=(j>>2)&7, m=j&3. pw1's K-dim is permuted identically (GEMM-invariant).
__global__ __launch_bounds__(256) void k0_cvt(const float* __restrict__ w1,
        const float* __restrict__ w2,
        const float* __restrict__ pw1, const float* __restrict__ pw2,
        __hip_bfloat16* __restrict__ w1b, __hip_bfloat16* __restrict__ w2b,
        __hip_bfloat16* __restrict__ mw1b, __hip_bfloat16* __restrict__ mw2b) {
    int i = blockIdx.x * 256 + threadIdx.x;   // 32768 threads
    if (i < CMID * DIM) w1b[i] = __float2bfloat16(w1[i]);
    if (i < NWP * CMID)
        w2b[i] = (i < NW * CMID) ? __float2bfloat16(w2[i]) : __float2bfloat16(0.f);
    {
        int f = i >> 7, j = i & 127;
        int qq = j >> 5, gg = (j >> 2) & 7, mm = j & 3;
        mw1b[i] = __float2bfloat16(pw1[f * 128 + gg * 16 + qq + 4 * mm]);
    }
    mw2b[i] = __float2bfloat16(pw2[i]);
}

// ---- K2 fused: conv1 MFMA; conv2 MFMA; involution (pk f16); LN; yln_p bf16 ----
__global__ __launch_bounds__(256, 3) void k2_fused(const float* __restrict__ x,
        const __hip_bfloat16* __restrict__ w1b, const float* __restrict__ b1v,
        const float* __restrict__ bng, const float* __restrict__ bnb,
        const float* __restrict__ bnm, const float* __restrict__ bnv,
        const __hip_bfloat16* __restrict__ w2b, const float* __restrict__ b2v,
        const float* __restrict__ lng, const float* __restrict__ lnb,
        __hip_bfloat16* __restrict__ yln) {
    __shared__ h2v  xp2[2][8][7][72];            // 31.5 KB, double-buffered
    __shared__ h2v  wgt2[49][66];                // 12.9 KB (dup f16 pairs)
    __shared__ __hip_bfloat16 tsh[64][32];       // 4 KB
    __shared__ float ps[4][64], pss[4][64];      // 2 KB
    __shared__ float mu_s[64], rs_s[64];         // 0.5 KB   (total ~50.6 KB -> 3 blocks/CU)
    int b = blockIdx.x & 7, h = blockIdx.x >> 3;   // XCD-aware: batch b -> XCD b
    int tid = threadIdx.x, lane = tid & 63, wid = tid >> 6;
    int l15 = lane & 15, l4 = lane >> 4;
    int m0 = wid * 16;
    int w = lane, q = wid;
    size_t pbase = (size_t)b * 4096 + (size_t)h * 64;

    // ---- staging geometry: g-invariant, precomputed once ----
    unsigned smask = 0;
    int goff[16];
    int ldso[16];
#pragma unroll
    for (int it = 0; it < 16; ++it) {
        int i = tid + it * 256;
        int ccp = i / 490;
        int rem = i - ccp * 490;
        int r = rem / 70, col = rem - r * 70;
        int hh = h + r - PADn, wc = col - PADn;
        bool ok = (i < 3920) & ((unsigned)hh < (unsigned)Hs) & ((unsigned)wc < (unsigned)Ws);
        smask |= (unsigned)ok << it;
        goff[it] = ok ? (((b * DIM + ccp) * Hs + hh) * Ws + wc) : 0;
        ldso[it] = ccp * 504 + r * 72 + col;
    }
    h2v* xpf = &xp2[0][0][0][0];

    auto stage = [&](int g, int buf) {
        const float* xg = x + g * 65536;           // + g*GC*Hs*Ws
        h2v* xb = xpf + buf * 4032;
#pragma unroll
        for (int hf = 0; hf < 2; ++hf) {
            float v0[8], v1[8];
#pragma unroll
            for (int e = 0; e < 8; ++e) {
                int it = hf * 8 + e;
                bool ok = (smask >> it) & 1u;
                v0[e] = ok ? xg[goff[it]] : 0.f;
                v1[e] = ok ? xg[goff[it] + 32768] : 0.f;   // +8 channels
            }
#pragma unroll
            for (int e = 0; e < 8; ++e) {
                int it = hf * 8 + e;
                if (it < 15 || tid < 80)                    // i < 3920
                    xb[ldso[it]] = (h2v){(_Float16)v0[e], (_Float16)v1[e]};
            }
        }
    };

    // ---- conv1 via MFMA ----
    bf16x8 afr[4];
#pragma unroll
    for (int ks = 0; ks < 4; ++ks)
#pragma unroll
        for (int i = 0; i < 8; ++i) {
            int c = ks * 32 + l4 * 8 + i;
            afr[ks][i] = tobf(x[(((size_t)b * DIM + c) * Hs + h) * Ws + m0 + l15]);
        }

    stage(0, 0);   // overlap group-0 staging with conv1

    f32x4 acc1[2];
#pragma unroll
    for (int nt = 0; nt < 2; ++nt) acc1[nt] = (f32x4){0.f, 0.f, 0.f, 0.f};
#pragma unroll
    for (int nt = 0; nt < 2; ++nt)
#pragma unroll
        for (int ks = 0; ks < 4; ++ks) {
            bf16x8 bf = *(const bf16x8*)&w1b[(nt * 16 + l15) * DIM + ks * 32 + l4 * 8];
            acc1[nt] = mfma16(afr[ks], bf, acc1[nt]);
        }
#pragma unroll
    for (int nt = 0; nt < 2; ++nt) {
        int o = nt * 16 + l15;
        float sc = bng[o] * rsqrtf(bnv[o] + 1e-5f);
        float sh = bnb[o] - bnm[o] * sc;
        float bv = b1v[o];
#pragma unroll
        for (int r = 0; r < 4; ++r) {
            float v = (acc1[nt][r] + bv) * sc + sh;
            tsh[m0 + l4 * 4 + r][o] = __float2bfloat16(fmaxf(v, 0.f));
        }
    }
    __syncthreads();   // tsh ready; stage(0) done

    bf16x8 a_t = *(const bf16x8*)&tsh[m0 + l15][l4 * 8];

    unsigned ypk[16];          // packed bf16 y: word g*2+hf = channels (g*16+q+8hf, +4)
    float s = 0.f, ss = 0.f;

#pragma unroll
    for (int g = 0; g < Gn; ++g) {
        int buf = g & 1;
        // ---- P1: conv2 via MFMA -> wgt2 ----
        f32x4 acc[4];
#pragma unroll
        for (int nt = 0; nt < 4; ++nt) acc[nt] = (f32x4){0.f, 0.f, 0.f, 0.f};
#pragma unroll
        for (int nt = 0; nt < 4; ++nt) {
            bf16x8 bf = *(const bf16x8*)&w2b[(size_t)(g * 49 + nt * 16 + l15) * CMID + l4 * 8];
            acc[nt] = mfma16(a_t, bf, acc[nt]);
        }
#pragma unroll
        for (int nt = 0; nt < 4; ++nt) {
            int p = nt * 16 + l15;
            if (p < 49) {
                float bias = b2v[g * 49 + p];
#pragma unroll
                for (int r = 0; r < 4; ++r) {
                    _Float16 hf16 = (_Float16)(acc[nt][r] + bias);
                    wgt2[p][m0 + l4 * 4 + r] = (h2v){hf16, hf16};
                }
            }
        }
        __syncthreads();   // wgt2 ready; xp2[buf] staging complete

        // ---- P2: prefetch next patch + involution into registers ----
        if (g < Gn - 1) stage(g + 1, buf ^ 1);

        h2v wv[49];
#pragma unroll
        for (int p = 0; p < 49; ++p) wv[p] = wgt2[p][w];

        float a00, a01, a10, a11;
#pragma unroll
        for (int pi = 0; pi < 2; ++pi) {
            int ccp = q + pi * 4;
            const h2v* xrow = xpf + buf * 4032 + ccp * 504;
            float accx = 0.f, accy = 0.f;
#pragma unroll
            for (int r = 0; r < 7; ++r) {
                h2v hacc = (h2v){(_Float16)0.f, (_Float16)0.f};
#pragma unroll
                for (int j = 0; j < 7; ++j)
                    hacc = wv[r * 7 + j] * xrow[r * 72 + w + j] + hacc;
                accx += (float)hacc.x;
                accy += (float)hacc.y;
            }
            if (pi == 0) { a00 = accx; a01 = accy; }
            else         { a10 = accx; a11 = accy; }
        }
        // channels: a00=g*16+q (m=0), a10=+4 (m=1), a01=+8 (m=2), a11=+12 (m=3)
        ypk[g * 2]     = su16(a00) | (su16(a10) << 16);
        ypk[g * 2 + 1] = su16(a01) | (su16(a11) << 16);
        s += (a00 + a10) + (a01 + a11);
        ss = fmaf(a00, a00, fmaf(a10, a10, fmaf(a01, a01, fmaf(a11, a11, ss))));
        __syncthreads();   // next-group staging done block-wide; wgt2 free
    }

    // ---- LayerNorm (partials from registers) ----
    ps[q][w] = s; pss[q][w] = ss;
    __syncthreads();
    if (tid < 64) {
        float sa = ps[0][tid] + ps[1][tid] + ps[2][tid] + ps[3][tid];
        float sb = pss[0][tid] + pss[1][tid] + pss[2][tid] + pss[3][tid];
        float mu = sa * (1.f / DIM);
        float var = sb * (1.f / DIM) - mu * mu;
        mu_s[tid] = mu;
        rs_s[tid] = rsqrtf(var + 1e-6f);
    }
    __syncthreads();
    float mu = mu_s[w], rs = rs_s[w];
    unsigned wds[16];
#pragma unroll
    for (int g = 0; g < 8; ++g)
#pragma unroll
        for (int hf = 0; hf < 2; ++hf) {
            unsigned wk = ypk[g * 2 + hf];
            float lo = __uint_as_float(wk << 16);
            float hi = __uint_as_float(wk & 0xffff0000u);
            int c0 = g * 16 + q + hf * 8, c1 = c0 + 4;
            lo = (lo - mu) * rs * lng[c0] + lnb[c0];
            hi = (hi - mu) * rs * lng[c1] + lnb[c1];
            wds[g * 2 + hf] = su16(lo) | (su16(hi) << 16);
        }
    __hip_bfloat16* dst = yln + (pbase + w) * DIM + q * 32;
#pragma unroll
    for (int c4 = 0; c4 < 4; ++c4) {
        uint4 vv = {wds[c4 * 4], wds[c4 * 4 + 1], wds[c4 * 4 + 2], wds[c4 * 4 + 3]};
        *(uint4*)&dst[c4 * 8] = vv;
    }
}

// ---------------- K3: MLP via bf16 MFMA + residual (no barriers) ----------------
__global__ __launch_bounds__(256, 3) void k3_mlp_mfma(
        const __hip_bfloat16* __restrict__ yln,   // [P][128] bf16 (permuted channels)
        const float* __restrict__ x,
        const __hip_bfloat16* __restrict__ w1b,   // [256][128] bf16, K-permuted
        const float* __restrict__ b1v,
        const __hip_bfloat16* __restrict__ w2b,   // [128][256] bf16
        const float* __restrict__ b2v,
        float* __restrict__ out) {
    __shared__ __align__(16) __hip_bfloat16 zsh[4][16][264];   // 33.8 KB, wave-private slices

    int b = blockIdx.x & 7, h = blockIdx.x >> 3;   // XCD-aware
    int tid = threadIdx.x;
    int lane = tid & 63, wid = tid >> 6;
    int l15 = lane & 15, l4 = lane >> 4;
    int m0 = wid * 16;
    size_t pbase = ((size_t)b * Hs + h) * Ws;

    // A-frags straight from global (each element read exactly once)
    bf16x8 a[4];
#pragma unroll
    for (int ks = 0; ks < 4; ++ks)
        a[ks] = *(const bf16x8*)&yln[(pbase + m0 + l15) * DIM + ks * 32 + l4 * 8];

    f32x4 acc[16];
#pragma unroll
    for (int n = 0; n < 16; ++n) acc[n] = (f32x4){0.f, 0.f, 0.f, 0.f};
#pragma unroll
    for (int ks = 0; ks < 4; ++ks)
#pragma unroll
        for (int n = 0; n < 16; ++n) {
            bf16x8 bf = *(const bf16x8*)&w1b[(n * 16 + l15) * DIM + ks * 32 + l4 * 8];
            acc[n] = mfma16(a[ks], bf, acc[n]);
        }

#pragma unroll
    for (int n = 0; n < 16; ++n) {
        float bv = b1v[n * 16 + l15];
#pragma unroll
        for (int r = 0; r < 4; ++r) {
            float v = acc[n][r] + bv;
            v = v * 0.5f * (1.f + erff(v * 0.70710678118f));
            zsh[wid][l4 * 4 + r][n * 16 + l15] = __float2bfloat16(v);
        }
    }

    f32x4 acc2[8];
#pragma unroll
    for (int n = 0; n < 8; ++n) acc2[n] = (f32x4){0.f, 0.f, 0.f, 0.f};
#pragma unroll
    for (int ks = 0; ks < 8; ++ks) {
        bf16x8 az = *(const bf16x8*)&zsh[wid][l15][ks * 32 + l4 * 8];
#pragma unroll
        for (int n = 0; n < 8; ++n) {
            bf16x8 bf = *(const bf16x8*)&w2b[(n * 16 + l15) * 256 + ks * 32 + l4 * 8];
            acc2[n] = mfma16(az, bf, acc2[n]);
        }
    }

    // direct store + residual (batched 16B loads, then 16B stores)
    float4 xr[8];
#pragma unroll
    for (int n = 0; n < 8; ++n) {
        int c = n * 16 + l15;
        xr[n] = *(const float4*)&x[(((size_t)b * DIM + c) * Hs + h) * Ws + m0 + l4 * 4];
    }
#pragma unroll
    for (int n = 0; n < 8; ++n) {
        int c = n * 16 + l15;
        float bv = b2v[c];
        size_t gi = (((size_t)b * DIM + c) * Hs + h) * Ws + m0 + l4 * 4;
        float4 o;
        o.x = acc2[n][0] + bv + xr[n].x;
        o.y = acc2[n][1] + bv + xr[n].y;
        o.z = acc2[n][2] + bv + xr[n].z;
        o.w = acc2[n][3] + bv + xr[n].w;
        *(float4*)&out[gi] = o;
    }
}

extern "C" void kernel_launch(void* const* d_in, const int* in_sizes, int n_in,
                              void* d_out, int out_size, void* d_ws, size_t ws_size,
                              hipStream_t stream) {
    const float* x       = (const float*)d_in[0];
    const float* conv1_w = (const float*)d_in[1];
    const float* conv1_b = (const float*)d_in[2];
    const float* bn_g    = (const float*)d_in[3];
    const float* bn_b    = (const float*)d_in[4];
    const float* bn_mean = (const float*)d_in[5];
    const float* bn_var  = (const float*)d_in[6];
    const float* conv2_w = (const float*)d_in[7];
    const float* conv2_b = (const float*)d_in[8];
    const float* ln_g    = (const float*)d_in[9];
    const float* ln_b    = (const float*)d_in[10];
    const float* pw1_w   = (const float*)d_in[11];
    const float* pw1_b   = (const float*)d_in[12];
    const float* pw2_w   = (const float*)d_in[13];
    const float* pw2_b   = (const float*)d_in[14];
    float* out = (float*)d_out;

    char* ws = (char*)d_ws;
    __hip_bfloat16* y_ln = (__hip_bfloat16*)ws;                      // 8 MB
    __hip_bfloat16* w1b  = (__hip_bfloat16*)(ws + 8388608);          // 8 KB
    __hip_bfloat16* w2b  = (__hip_bfloat16*)(ws + 8396800);          // 26 KB
    __hip_bfloat16* mw1b = (__hip_bfloat16*)(ws + 8423424);          // 64 KB (permuted)
    __hip_bfloat16* mw2b = (__hip_bfloat16*)(ws + 8488960);          // 64 KB

    dim3 block(256);
    hipLaunchKernelGGL(k0_cvt, dim3(128), block, 0, stream,
                       conv1_w, conv2_w, pw1_w, pw2_w, w1b, w2b, mw1b, mw2b);
    hipLaunchKernelGGL(k2_fused, dim3(Bn * Hs), block, 0, stream,
                       x, w1b, conv1_b, bn_g, bn_b, bn_mean, bn_var,
                       w2b, conv2_b, ln_g, ln_b, y_ln);
    hipLaunchKernelGGL(k3_mlp_mfma, dim3(Bn * Hs), block, 0, stream,
                       y_ln, x, mw1b, pw1_b, mw2b, pw2_b, out);
}

// Round 7
// 334.151 us; speedup vs baseline: 1.2517x; 1.2517x over previous
//
#include <hip/hip_runtime.h>
#include <hip/hip_bf16.h>
#include <math.h>

#define Bn   8
#define DIM  128
#define Hs   64
#define Ws   64
#define PADn 3
#define GC   16
#define Gn   8
#define CMID 32    // DIM/RED
#define NW   392   // K*K*G
#define NWP  416   // w2b padded rows

typedef __bf16 bf16x8 __attribute__((ext_vector_type(8)));
typedef float  f32x4  __attribute__((ext_vector_type(4)));
typedef _Float16 h2v  __attribute__((ext_vector_type(2)));

__device__ __forceinline__ f32x4 mfma16(bf16x8 a, bf16x8 b, f32x4 c) {
    return __builtin_amdgcn_mfma_f32_16x16x32_bf16(a, b, c, 0, 0, 0);
}

__device__ __forceinline__ __bf16 tobf(float v) {
    __hip_bfloat16 h = __float2bfloat16(v);
    return *reinterpret_cast<__bf16*>(&h);
}

__device__ __forceinline__ unsigned su16(float f) {
    __hip_bfloat16 h = __float2bfloat16(f);
    return (unsigned)*reinterpret_cast<unsigned short*>(&h);
}

// ---------------- K0: convert weights to bf16 (+ permute pw1 K-dim) ----------------
// y is written permuted: y_p[pix][j] = y[pix][c(j)], c(j) = g*16 + q + 4m,
// q=j>>5, g=(j>>2)&7, m=j&3. pw1's K-dim is permuted identically (GEMM-invariant).
__global__ __launch_bounds__(256) void k0_cvt(const float* __restrict__ w1,
        const float* __restrict__ w2,
        const float* __restrict__ pw1, const float* __restrict__ pw2,
        __hip_bfloat16* __restrict__ w1b, __hip_bfloat16* __restrict__ w2b,
        __hip_bfloat16* __restrict__ mw1b, __hip_bfloat16* __restrict__ mw2b) {
    int i = blockIdx.x * 256 + threadIdx.x;   // 32768 threads
    if (i < CMID * DIM) w1b[i] = __float2bfloat16(w1[i]);
    if (i < NWP * CMID)
        w2b[i] = (i < NW * CMID) ? __float2bfloat16(w2[i]) : __float2bfloat16(0.f);
    {
        int f = i >> 7, j = i & 127;
        int qq = j >> 5, gg = (j >> 2) & 7, mm = j & 3;
        mw1b[i] = __float2bfloat16(pw1[f * 128 + gg * 16 + qq + 4 * mm]);
    }
    mw2b[i] = __float2bfloat16(pw2[i]);
}

// ---- K2 fused: conv1 MFMA; conv2 MFMA; involution (pk f16); LN; yln_p bf16 ----
__global__ __launch_bounds__(256) void k2_fused(const float* __restrict__ x,
        const __hip_bfloat16* __restrict__ w1b, const float* __restrict__ b1v,
        const float* __restrict__ bng, const float* __restrict__ bnb,
        const float* __restrict__ bnm, const float* __restrict__ bnv,
        const __hip_bfloat16* __restrict__ w2b, const float* __restrict__ b2v,
        const float* __restrict__ lng, const float* __restrict__ lnb,
        __hip_bfloat16* __restrict__ yln) {
    __shared__ h2v  xp2[2][8][7][72];            // 31.5 KB, double-buffered
    __shared__ h2v  wgt2[49][66];                // 12.9 KB (dup f16 pairs)
    __shared__ __hip_bfloat16 tsh[64][32];       // 4 KB
    __shared__ float ps[4][64], pss[4][64];      // 2 KB
    __shared__ float mu_s[64], rs_s[64];         // 0.5 KB  (total ~50.6 KB)
    int b = blockIdx.x & 7, h = blockIdx.x >> 3;   // XCD-aware: batch b -> XCD b
    int tid = threadIdx.x, lane = tid & 63, wid = tid >> 6;
    int l15 = lane & 15, l4 = lane >> 4;
    int m0 = wid * 16;
    int w = lane, q = wid;
    size_t pbase = (size_t)b * 4096 + (size_t)h * 64;

    h2v* xpf = &xp2[0][0][0][0];

    // batched stage: all loads issued before writes; geometry recomputed inline
    auto stage = [&](int g, int buf) {
        const float* xg = x + ((size_t)b * DIM + g * GC) * (Hs * Ws);
        h2v* xb = xpf + buf * 4032;
#pragma unroll
        for (int hf = 0; hf < 2; ++hf) {
            float v0[8], v1[8];
#pragma unroll
            for (int e = 0; e < 8; ++e) {
                int i = tid + (hf * 8 + e) * 256;
                int ccp = i / 490;
                int rem = i - ccp * 490;
                int r = rem / 70, col = rem - r * 70;
                int hh = h + r - PADn, wc = col - PADn;
                bool ok = (i < 3920) & ((unsigned)hh < (unsigned)Hs) &
                          ((unsigned)wc < (unsigned)Ws);
                int off = ok ? ((ccp * Hs + hh) * Ws + wc) : 0;
                v0[e] = ok ? xg[off] : 0.f;
                v1[e] = ok ? xg[off + 8 * Hs * Ws] : 0.f;
            }
#pragma unroll
            for (int e = 0; e < 8; ++e) {
                int i = tid + (hf * 8 + e) * 256;
                if (i < 3920) {
                    int ccp = i / 490;
                    int rem = i - ccp * 490;
                    int r = rem / 70, col = rem - r * 70;
                    xb[ccp * 504 + r * 72 + col] = (h2v){(_Float16)v0[e], (_Float16)v1[e]};
                }
            }
        }
    };

    // ---- conv1 via MFMA ----
    bf16x8 afr[4];
#pragma unroll
    for (int ks = 0; ks < 4; ++ks)
#pragma unroll
        for (int i = 0; i < 8; ++i) {
            int c = ks * 32 + l4 * 8 + i;
            afr[ks][i] = tobf(x[(((size_t)b * DIM + c) * Hs + h) * Ws + m0 + l15]);
        }

    stage(0, 0);   // overlap group-0 staging with conv1

    f32x4 acc1[2];
#pragma unroll
    for (int nt = 0; nt < 2; ++nt) acc1[nt] = (f32x4){0.f, 0.f, 0.f, 0.f};
#pragma unroll
    for (int nt = 0; nt < 2; ++nt)
#pragma unroll
        for (int ks = 0; ks < 4; ++ks) {
            bf16x8 bf = *(const bf16x8*)&w1b[(nt * 16 + l15) * DIM + ks * 32 + l4 * 8];
            acc1[nt] = mfma16(afr[ks], bf, acc1[nt]);
        }
#pragma unroll
    for (int nt = 0; nt < 2; ++nt) {
        int o = nt * 16 + l15;
        float sc = bng[o] * rsqrtf(bnv[o] + 1e-5f);
        float sh = bnb[o] - bnm[o] * sc;
        float bv = b1v[o];
#pragma unroll
        for (int r = 0; r < 4; ++r) {
            float v = (acc1[nt][r] + bv) * sc + sh;
            tsh[m0 + l4 * 4 + r][o] = __float2bfloat16(fmaxf(v, 0.f));
        }
    }
    __syncthreads();   // tsh ready; stage(0) done

    bf16x8 a_t = *(const bf16x8*)&tsh[m0 + l15][l4 * 8];

    unsigned ypk[16];          // packed bf16 y: word g*2+hf = channels (g*16+q+8hf, +4)
    float s = 0.f, ss = 0.f;

#pragma unroll
    for (int g = 0; g < Gn; ++g) {
        int buf = g & 1;
        // ---- P1: conv2 via MFMA -> wgt2 ----
        f32x4 acc[4];
#pragma unroll
        for (int nt = 0; nt < 4; ++nt) acc[nt] = (f32x4){0.f, 0.f, 0.f, 0.f};
#pragma unroll
        for (int nt = 0; nt < 4; ++nt) {
            bf16x8 bf = *(const bf16x8*)&w2b[(size_t)(g * 49 + nt * 16 + l15) * CMID + l4 * 8];
            acc[nt] = mfma16(a_t, bf, acc[nt]);
        }
#pragma unroll
        for (int nt = 0; nt < 4; ++nt) {
            int p = nt * 16 + l15;
            if (p < 49) {
                float bias = b2v[g * 49 + p];
#pragma unroll
                for (int r = 0; r < 4; ++r) {
                    _Float16 hf16 = (_Float16)(acc[nt][r] + bias);
                    wgt2[p][m0 + l4 * 4 + r] = (h2v){hf16, hf16};
                }
            }
        }
        __syncthreads();   // wgt2 ready; xp2[buf] staging complete

        // ---- P2: prefetch next patch + involution into registers ----
        if (g < Gn - 1) stage(g + 1, buf ^ 1);

        h2v wv[49];
#pragma unroll
        for (int p = 0; p < 49; ++p) wv[p] = wgt2[p][w];

        float a00, a01, a10, a11;
#pragma unroll
        for (int pi = 0; pi < 2; ++pi) {
            int ccp = q + pi * 4;
            const h2v* xrow = xpf + buf * 4032 + ccp * 504;
            float accx = 0.f, accy = 0.f;
#pragma unroll
            for (int r = 0; r < 7; ++r) {
                h2v hacc = (h2v){(_Float16)0.f, (_Float16)0.f};
#pragma unroll
                for (int j = 0; j < 7; ++j)
                    hacc = wv[r * 7 + j] * xrow[r * 72 + w + j] + hacc;
                accx += (float)hacc.x;
                accy += (float)hacc.y;
            }
            if (pi == 0) { a00 = accx; a01 = accy; }
            else         { a10 = accx; a11 = accy; }
        }
        // channels: a00=g*16+q (m=0), a10=+4 (m=1), a01=+8 (m=2), a11=+12 (m=3)
        ypk[g * 2]     = su16(a00) | (su16(a10) << 16);
        ypk[g * 2 + 1] = su16(a01) | (su16(a11) << 16);
        s += (a00 + a10) + (a01 + a11);
        ss = fmaf(a00, a00, fmaf(a10, a10, fmaf(a01, a01, fmaf(a11, a11, ss))));
        __syncthreads();   // next-group staging done block-wide; wgt2 free
    }

    // ---- LayerNorm (partials from registers) ----
    ps[q][w] = s; pss[q][w] = ss;
    __syncthreads();
    if (tid < 64) {
        float sa = ps[0][tid] + ps[1][tid] + ps[2][tid] + ps[3][tid];
        float sb = pss[0][tid] + pss[1][tid] + pss[2][tid] + pss[3][tid];
        float mu = sa * (1.f / DIM);
        float var = sb * (1.f / DIM) - mu * mu;
        mu_s[tid] = mu;
        rs_s[tid] = rsqrtf(var + 1e-6f);
    }
    __syncthreads();
    float mu = mu_s[w], rs = rs_s[w];
    unsigned wds[16];
#pragma unroll
    for (int g = 0; g < 8; ++g)
#pragma unroll
        for (int hf = 0; hf < 2; ++hf) {
            unsigned wk = ypk[g * 2 + hf];
            float lo = __uint_as_float(wk << 16);
            float hi = __uint_as_float(wk & 0xffff0000u);
            int c0 = g * 16 + q + hf * 8, c1 = c0 + 4;
            lo = (lo - mu) * rs * lng[c0] + lnb[c0];
            hi = (hi - mu) * rs * lng[c1] + lnb[c1];
            wds[g * 2 + hf] = su16(lo) | (su16(hi) << 16);
        }
    __hip_bfloat16* dst = yln + (pbase + w) * DIM + q * 32;
#pragma unroll
    for (int c4 = 0; c4 < 4; ++c4) {
        uint4 vv = {wds[c4 * 4], wds[c4 * 4 + 1], wds[c4 * 4 + 2], wds[c4 * 4 + 3]};
        *(uint4*)&dst[c4 * 8] = vv;
    }
}

// ---------------- K3: MLP via bf16 MFMA + residual (no barriers) ----------------
__global__ __launch_bounds__(256) void k3_mlp_mfma(
        const __hip_bfloat16* __restrict__ yln,   // [P][128] bf16 (permuted channels)
        const float* __restrict__ x,
        const __hip_bfloat16* __restrict__ w1b,   // [256][128] bf16, K-permuted
        const float* __restrict__ b1v,
        const __hip_bfloat16* __restrict__ w2b,   // [128][256] bf16
        const float* __restrict__ b2v,
        float* __restrict__ out) {
    __shared__ __align__(16) __hip_bfloat16 zsh[4][16][264];   // 33.8 KB, wave-private slices

    int b = blockIdx.x & 7, h = blockIdx.x >> 3;   // XCD-aware
    int tid = threadIdx.x;
    int lane = tid & 63, wid = tid >> 6;
    int l15 = lane & 15, l4 = lane >> 4;
    int m0 = wid * 16;
    size_t pbase = ((size_t)b * Hs + h) * Ws;

    // A-frags straight from global (each element read exactly once)
    bf16x8 a[4];
#pragma unroll
    for (int ks = 0; ks < 4; ++ks)
        a[ks] = *(const bf16x8*)&yln[(pbase + m0 + l15) * DIM + ks * 32 + l4 * 8];

    f32x4 acc[16];
#pragma unroll
    for (int n = 0; n < 16; ++n) acc[n] = (f32x4){0.f, 0.f, 0.f, 0.f};
#pragma unroll
    for (int ks = 0; ks < 4; ++ks)
#pragma unroll
        for (int n = 0; n < 16; ++n) {
            bf16x8 bf = *(const bf16x8*)&w1b[(n * 16 + l15) * DIM + ks * 32 + l4 * 8];
            acc[n] = mfma16(a[ks], bf, acc[n]);
        }

#pragma unroll
    for (int n = 0; n < 16; ++n) {
        float bv = b1v[n * 16 + l15];
#pragma unroll
        for (int r = 0; r < 4; ++r) {
            float v = acc[n][r] + bv;
            v = v * 0.5f * (1.f + erff(v * 0.70710678118f));
            zsh[wid][l4 * 4 + r][n * 16 + l15] = __float2bfloat16(v);
        }
    }

    f32x4 acc2[8];
#pragma unroll
    for (int n = 0; n < 8; ++n) acc2[n] = (f32x4){0.f, 0.f, 0.f, 0.f};
#pragma unroll
    for (int ks = 0; ks < 8; ++ks) {
        bf16x8 az = *(const bf16x8*)&zsh[wid][l15][ks * 32 + l4 * 8];
#pragma unroll
        for (int n = 0; n < 8; ++n) {
            bf16x8 bf = *(const bf16x8*)&w2b[(n * 16 + l15) * 256 + ks * 32 + l4 * 8];
            acc2[n] = mfma16(az, bf, acc2[n]);
        }
    }

    // direct store + residual (batched 16B loads, then 16B stores)
    float4 xr[8];
#pragma unroll
    for (int n = 0; n < 8; ++n) {
        int c = n * 16 + l15;
        xr[n] = *(const float4*)&x[(((size_t)b * DIM + c) * Hs + h) * Ws + m0 + l4 * 4];
    }
#pragma unroll
    for (int n = 0; n < 8; ++n) {
        int c = n * 16 + l15;
        float bv = b2v[c];
        size_t gi = (((size_t)b * DIM + c) * Hs + h) * Ws + m0 + l4 * 4;
        float4 o;
        o.x = acc2[n][0] + bv + xr[n].x;
        o.y = acc2[n][1] + bv + xr[n].y;
        o.z = acc2[n][2] + bv + xr[n].z;
        o.w = acc2[n][3] + bv + xr[n].w;
        *(float4*)&out[gi] = o;
    }
}

extern "C" void kernel_launch(void* const* d_in, const int* in_sizes, int n_in,
                              void* d_out, int out_size, void* d_ws, size_t ws_size,
                              hipStream_t stream) {
    const float* x       = (const float*)d_in[0];
    const float* conv1_w = (const float*)d_in[1];
    const float* conv1_b = (const float*)d_in[2];
    const float* bn_g    = (const float*)d_in[3];
    const float* bn_b    = (const float*)d_in[4];
    const float* bn_mean = (const float*)d_in[5];
    const float* bn_var  = (const float*)d_in[6];
    const float* conv2_w = (const float*)d_in[7];
    const float* conv2_b = (const float*)d_in[8];
    const float* ln_g    = (const float*)d_in[9];
    const float* ln_b    = (const float*)d_in[10];
    const float* pw1_w   = (const float*)d_in[11];
    const float* pw1_b   = (const float*)d_in[12];
    const float* pw2_w   = (const float*)d_in[13];
    const float* pw2_b   = (const float*)d_in[14];
    float* out = (float*)d_out;

    char* ws = (char*)d_ws;
    __hip_bfloat16* y_ln = (__hip_bfloat16*)ws;                      // 8 MB
    __hip_bfloat16* w1b  = (__hip_bfloat16*)(ws + 8388608);          // 8 KB
    __hip_bfloat16* w2b  = (__hip_bfloat16*)(ws + 8396800);          // 26 KB
    __hip_bfloat16* mw1b = (__hip_bfloat16*)(ws + 8423424);          // 64 KB (permuted)
    __hip_bfloat16* mw2b = (__hip_bfloat16*)(ws + 8488960);          // 64 KB

    dim3 block(256);
    hipLaunchKernelGGL(k0_cvt, dim3(128), block, 0, stream,
                       conv1_w, conv2_w, pw1_w, pw2_w, w1b, w2b, mw1b, mw2b);
    hipLaunchKernelGGL(k2_fused, dim3(Bn * Hs), block, 0, stream,
                       x, w1b, conv1_b, bn_g, bn_b, bn_mean, bn_var,
                       w2b, conv2_b, ln_g, ln_b, y_ln);
    hipLaunchKernelGGL(k3_mlp_mfma, dim3(Bn * Hs), block, 0, stream,
                       y_ln, x, mw1b, pw1_b, mw2b, pw2_b, out);
}

// Round 8
// 115.189 us; speedup vs baseline: 3.6311x; 2.9009x over previous
//
#include <hip/hip_runtime.h>
#include <hip/hip_bf16.h>
#include <math.h>

#define Bn   8
#define DIM  128
#define Hs   64
#define Ws   64
#define PADn 3
#define GC   16
#define Gn   8
#define CMID 32    // DIM/RED
#define NW   392   // K*K*G
#define NWP  416   // w2b padded rows

typedef __bf16 bf16x8 __attribute__((ext_vector_type(8)));
typedef float  f32x4  __attribute__((ext_vector_type(4)));
typedef _Float16 h2v  __attribute__((ext_vector_type(2)));

__device__ __forceinline__ f32x4 mfma16(bf16x8 a, bf16x8 b, f32x4 c) {
    return __builtin_amdgcn_mfma_f32_16x16x32_bf16(a, b, c, 0, 0, 0);
}

__device__ __forceinline__ __bf16 tobf(float v) {
    __hip_bfloat16 h = __float2bfloat16(v);
    return *reinterpret_cast<__bf16*>(&h);
}

__device__ __forceinline__ unsigned su16(float f) {
    __hip_bfloat16 h = __float2bfloat16(f);
    return (unsigned)*reinterpret_cast<unsigned short*>(&h);
}

// ---------------- K0: convert weights to bf16 (+ permute pw1 K-dim) ----------------
// y is written permuted: y_p[pix][j] = y[pix][c(j)], c(j) = g*16 + q + 4m,
// q=j>>5, g=(j>>2)&7, m=j&3. pw1's K-dim is permuted identically (GEMM-invariant).
__global__ __launch_bounds__(256) void k0_cvt(const float* __restrict__ w1,
        const float* __restrict__ w2,
        const float* __restrict__ pw1, const float* __restrict__ pw2,
        __hip_bfloat16* __restrict__ w1b, __hip_bfloat16* __restrict__ w2b,
        __hip_bfloat16* __restrict__ mw1b, __hip_bfloat16* __restrict__ mw2b) {
    int i = blockIdx.x * 256 + threadIdx.x;   // 32768 threads
    if (i < CMID * DIM) w1b[i] = __float2bfloat16(w1[i]);
    if (i < NWP * CMID)
        w2b[i] = (i < NW * CMID) ? __float2bfloat16(w2[i]) : __float2bfloat16(0.f);
    {
        int f = i >> 7, j = i & 127;
        int qq = j >> 5, gg = (j >> 2) & 7, mm = j & 3;
        mw1b[i] = __float2bfloat16(pw1[f * 128 + gg * 16 + qq + 4 * mm]);
    }
    mw2b[i] = __float2bfloat16(pw2[i]);
}

// ---- K2 fused: conv1 MFMA; conv2 MFMA; involution (pk f16); LN; yln_p bf16 ----
__global__ __launch_bounds__(256) void k2_fused(const float* __restrict__ x,
        const __hip_bfloat16* __restrict__ w1b, const float* __restrict__ b1v,
        const float* __restrict__ bng, const float* __restrict__ bnb,
        const float* __restrict__ bnm, const float* __restrict__ bnv,
        const __hip_bfloat16* __restrict__ w2b, const float* __restrict__ b2v,
        const float* __restrict__ lng, const float* __restrict__ lnb,
        __hip_bfloat16* __restrict__ yln) {
    __shared__ h2v  xp2[2][8][7][72];            // 31.5 KB, double-buffered
    __shared__ h2v  wgt2[49][66];                // 12.9 KB (dup f16 pairs)
    __shared__ __hip_bfloat16 tsh[64][32];       // 4 KB
    __shared__ float ps[4][64], pss[4][64];      // 2 KB
    __shared__ float mu_s[64], rs_s[64];         // 0.5 KB  (total ~50.6 KB)
    int b = blockIdx.x & 7, h = blockIdx.x >> 3;   // XCD-aware: batch b -> XCD b
    int tid = threadIdx.x, lane = tid & 63, wid = tid >> 6;
    int l15 = lane & 15, l4 = lane >> 4;
    int m0 = wid * 16;
    int w = lane, q = wid;
    size_t pbase = (size_t)b * 4096 + (size_t)h * 64;

    h2v* xpf = &xp2[0][0][0][0];

    // batched stage: all loads issued before writes; geometry recomputed inline
    auto stage = [&](int g, int buf) {
        const float* xg = x + ((size_t)b * DIM + g * GC) * (Hs * Ws);
        h2v* xb = xpf + buf * 4032;
#pragma unroll
        for (int hf = 0; hf < 2; ++hf) {
            float v0[8], v1[8];
#pragma unroll
            for (int e = 0; e < 8; ++e) {
                int i = tid + (hf * 8 + e) * 256;
                int ccp = i / 490;
                int rem = i - ccp * 490;
                int r = rem / 70, col = rem - r * 70;
                int hh = h + r - PADn, wc = col - PADn;
                bool ok = (i < 3920) & ((unsigned)hh < (unsigned)Hs) &
                          ((unsigned)wc < (unsigned)Ws);
                int off = ok ? ((ccp * Hs + hh) * Ws + wc) : 0;
                v0[e] = ok ? xg[off] : 0.f;
                v1[e] = ok ? xg[off + 8 * Hs * Ws] : 0.f;
            }
#pragma unroll
            for (int e = 0; e < 8; ++e) {
                int i = tid + (hf * 8 + e) * 256;
                if (i < 3920) {
                    int ccp = i / 490;
                    int rem = i - ccp * 490;
                    int r = rem / 70, col = rem - r * 70;
                    xb[ccp * 504 + r * 72 + col] = (h2v){(_Float16)v0[e], (_Float16)v1[e]};
                }
            }
        }
    };

    // ---- conv1 via MFMA ----
    bf16x8 afr[4];
#pragma unroll
    for (int ks = 0; ks < 4; ++ks)
#pragma unroll
        for (int i = 0; i < 8; ++i) {
            int c = ks * 32 + l4 * 8 + i;
            afr[ks][i] = tobf(x[(((size_t)b * DIM + c) * Hs + h) * Ws + m0 + l15]);
        }

    stage(0, 0);   // overlap group-0 staging with conv1

    f32x4 acc1[2];
#pragma unroll
    for (int nt = 0; nt < 2; ++nt) acc1[nt] = (f32x4){0.f, 0.f, 0.f, 0.f};
#pragma unroll
    for (int nt = 0; nt < 2; ++nt)
#pragma unroll
        for (int ks = 0; ks < 4; ++ks) {
            bf16x8 bf = *(const bf16x8*)&w1b[(nt * 16 + l15) * DIM + ks * 32 + l4 * 8];
            acc1[nt] = mfma16(afr[ks], bf, acc1[nt]);
        }
#pragma unroll
    for (int nt = 0; nt < 2; ++nt) {
        int o = nt * 16 + l15;
        float sc = bng[o] * rsqrtf(bnv[o] + 1e-5f);
        float sh = bnb[o] - bnm[o] * sc;
        float bv = b1v[o];
#pragma unroll
        for (int r = 0; r < 4; ++r) {
            float v = (acc1[nt][r] + bv) * sc + sh;
            tsh[m0 + l4 * 4 + r][o] = __float2bfloat16(fmaxf(v, 0.f));
        }
    }
    __syncthreads();   // tsh ready; stage(0) done

    bf16x8 a_t = *(const bf16x8*)&tsh[m0 + l15][l4 * 8];

    unsigned ypk[16];          // packed bf16 y: word g*2+hf = channels (g*16+q+8hf, +4)
    float s = 0.f, ss = 0.f;

    // ROLLED group loop — full unroll (R5/R6) ballooned live ranges -> 256 VGPR + scratch spill
#pragma unroll 1
    for (int g = 0; g < Gn; ++g) {
        int buf = g & 1;
        // ---- P1: conv2 via MFMA -> wgt2 ----
        f32x4 acc[4];
#pragma unroll
        for (int nt = 0; nt < 4; ++nt) acc[nt] = (f32x4){0.f, 0.f, 0.f, 0.f};
#pragma unroll
        for (int nt = 0; nt < 4; ++nt) {
            bf16x8 bf = *(const bf16x8*)&w2b[(size_t)(g * 49 + nt * 16 + l15) * CMID + l4 * 8];
            acc[nt] = mfma16(a_t, bf, acc[nt]);
        }
#pragma unroll
        for (int nt = 0; nt < 4; ++nt) {
            int p = nt * 16 + l15;
            if (p < 49) {
                float bias = b2v[g * 49 + p];
#pragma unroll
                for (int r = 0; r < 4; ++r) {
                    _Float16 hf16 = (_Float16)(acc[nt][r] + bias);
                    wgt2[p][m0 + l4 * 4 + r] = (h2v){hf16, hf16};
                }
            }
        }
        __syncthreads();   // wgt2 ready; xp2[buf] staging complete

        // ---- P2: prefetch next patch + involution into registers ----
        if (g < Gn - 1) stage(g + 1, buf ^ 1);

        h2v wv[49];
#pragma unroll
        for (int p = 0; p < 49; ++p) wv[p] = wgt2[p][w];

        float a00, a01, a10, a11;
#pragma unroll
        for (int pi = 0; pi < 2; ++pi) {
            int ccp = q + pi * 4;
            const h2v* xrow = xpf + buf * 4032 + ccp * 504;
            float accx = 0.f, accy = 0.f;
#pragma unroll
            for (int r = 0; r < 7; ++r) {
                h2v hacc = (h2v){(_Float16)0.f, (_Float16)0.f};
#pragma unroll
                for (int j = 0; j < 7; ++j)
                    hacc = wv[r * 7 + j] * xrow[r * 72 + w + j] + hacc;
                accx += (float)hacc.x;
                accy += (float)hacc.y;
            }
            if (pi == 0) { a00 = accx; a01 = accy; }
            else         { a10 = accx; a11 = accy; }
        }
        // channels: a00=g*16+q (m=0), a10=+4 (m=1), a01=+8 (m=2), a11=+12 (m=3)
        ypk[g * 2]     = su16(a00) | (su16(a10) << 16);
        ypk[g * 2 + 1] = su16(a01) | (su16(a11) << 16);
        s += (a00 + a10) + (a01 + a11);
        ss = fmaf(a00, a00, fmaf(a10, a10, fmaf(a01, a01, fmaf(a11, a11, ss))));
        __syncthreads();   // next-group staging done block-wide; wgt2 free
    }

    // ---- LayerNorm (partials from registers) ----
    ps[q][w] = s; pss[q][w] = ss;
    __syncthreads();
    if (tid < 64) {
        float sa = ps[0][tid] + ps[1][tid] + ps[2][tid] + ps[3][tid];
        float sb = pss[0][tid] + pss[1][tid] + pss[2][tid] + pss[3][tid];
        float mu = sa * (1.f / DIM);
        float var = sb * (1.f / DIM) - mu * mu;
        mu_s[tid] = mu;
        rs_s[tid] = rsqrtf(var + 1e-6f);
    }
    __syncthreads();
    float mu = mu_s[w], rs = rs_s[w];
    unsigned wds[16];
#pragma unroll
    for (int g = 0; g < 8; ++g)
#pragma unroll
        for (int hf = 0; hf < 2; ++hf) {
            unsigned wk = ypk[g * 2 + hf];
            float lo = __uint_as_float(wk << 16);
            float hi = __uint_as_float(wk & 0xffff0000u);
            int c0 = g * 16 + q + hf * 8, c1 = c0 + 4;
            lo = (lo - mu) * rs * lng[c0] + lnb[c0];
            hi = (hi - mu) * rs * lng[c1] + lnb[c1];
            wds[g * 2 + hf] = su16(lo) | (su16(hi) << 16);
        }
    __hip_bfloat16* dst = yln + (pbase + w) * DIM + q * 32;
#pragma unroll
    for (int c4 = 0; c4 < 4; ++c4) {
        uint4 vv = {wds[c4 * 4], wds[c4 * 4 + 1], wds[c4 * 4 + 2], wds[c4 * 4 + 3]};
        *(uint4*)&dst[c4 * 8] = vv;
    }
}

// ---------------- K3: MLP via bf16 MFMA + residual (no barriers) ----------------
__global__ __launch_bounds__(256) void k3_mlp_mfma(
        const __hip_bfloat16* __restrict__ yln,   // [P][128] bf16 (permuted channels)
        const float* __restrict__ x,
        const __hip_bfloat16* __restrict__ w1b,   // [256][128] bf16, K-permuted
        const float* __restrict__ b1v,
        const __hip_bfloat16* __restrict__ w2b,   // [128][256] bf16
        const float* __restrict__ b2v,
        float* __restrict__ out) {
    __shared__ __align__(16) __hip_bfloat16 zsh[4][16][264];   // 33.8 KB, wave-private slices

    int b = blockIdx.x & 7, h = blockIdx.x >> 3;   // XCD-aware
    int tid = threadIdx.x;
    int lane = tid & 63, wid = tid >> 6;
    int l15 = lane & 15, l4 = lane >> 4;
    int m0 = wid * 16;
    size_t pbase = ((size_t)b * Hs + h) * Ws;

    // A-frags straight from global (each element read exactly once)
    bf16x8 a[4];
#pragma unroll
    for (int ks = 0; ks < 4; ++ks)
        a[ks] = *(const bf16x8*)&yln[(pbase + m0 + l15) * DIM + ks * 32 + l4 * 8];

    f32x4 acc[16];
#pragma unroll
    for (int n = 0; n < 16; ++n) acc[n] = (f32x4){0.f, 0.f, 0.f, 0.f};
#pragma unroll
    for (int ks = 0; ks < 4; ++ks)
#pragma unroll
        for (int n = 0; n < 16; ++n) {
            bf16x8 bf = *(const bf16x8*)&w1b[(n * 16 + l15) * DIM + ks * 32 + l4 * 8];
            acc[n] = mfma16(a[ks], bf, acc[n]);
        }

#pragma unroll
    for (int n = 0; n < 16; ++n) {
        float bv = b1v[n * 16 + l15];
#pragma unroll
        for (int r = 0; r < 4; ++r) {
            float v = acc[n][r] + bv;
            v = v * 0.5f * (1.f + erff(v * 0.70710678118f));
            zsh[wid][l4 * 4 + r][n * 16 + l15] = __float2bfloat16(v);
        }
    }

    f32x4 acc2[8];
#pragma unroll
    for (int n = 0; n < 8; ++n) acc2[n] = (f32x4){0.f, 0.f, 0.f, 0.f};
#pragma unroll
    for (int ks = 0; ks < 8; ++ks) {
        bf16x8 az = *(const bf16x8*)&zsh[wid][l15][ks * 32 + l4 * 8];
#pragma unroll
        for (int n = 0; n < 8; ++n) {
            bf16x8 bf = *(const bf16x8*)&w2b[(n * 16 + l15) * 256 + ks * 32 + l4 * 8];
            acc2[n] = mfma16(az, bf, acc2[n]);
        }
    }

    // direct store + residual (batched 16B loads, then 16B stores)
    float4 xr[8];
#pragma unroll
    for (int n = 0; n < 8; ++n) {
        int c = n * 16 + l15;
        xr[n] = *(const float4*)&x[(((size_t)b * DIM + c) * Hs + h) * Ws + m0 + l4 * 4];
    }
#pragma unroll
    for (int n = 0; n < 8; ++n) {
        int c = n * 16 + l15;
        float bv = b2v[c];
        size_t gi = (((size_t)b * DIM + c) * Hs + h) * Ws + m0 + l4 * 4;
        float4 o;
        o.x = acc2[n][0] + bv + xr[n].x;
        o.y = acc2[n][1] + bv + xr[n].y;
        o.z = acc2[n][2] + bv + xr[n].z;
        o.w = acc2[n][3] + bv + xr[n].w;
        *(float4*)&out[gi] = o;
    }
}

extern "C" void kernel_launch(void* const* d_in, const int* in_sizes, int n_in,
                              void* d_out, int out_size, void* d_ws, size_t ws_size,
                              hipStream_t stream) {
    const float* x       = (const float*)d_in[0];
    const float* conv1_w = (const float*)d_in[1];
    const float* conv1_b = (const float*)d_in[2];
    const float* bn_g    = (const float*)d_in[3];
    const float* bn_b    = (const float*)d_in[4];
    const float* bn_mean = (const float*)d_in[5];
    const float* bn_var  = (const float*)d_in[6];
    const float* conv2_w = (const float*)d_in[7];
    const float* conv2_b = (const float*)d_in[8];
    const float* ln_g    = (const float*)d_in[9];
    const float* ln_b    = (const float*)d_in[10];
    const float* pw1_w   = (const float*)d_in[11];
    const float* pw1_b   = (const float*)d_in[12];
    const float* pw2_w   = (const float*)d_in[13];
    const float* pw2_b   = (const float*)d_in[14];
    float* out = (float*)d_out;

    char* ws = (char*)d_ws;
    __hip_bfloat16* y_ln = (__hip_bfloat16*)ws;                      // 8 MB
    __hip_bfloat16* w1b  = (__hip_bfloat16*)(ws + 8388608);          // 8 KB
    __hip_bfloat16* w2b  = (__hip_bfloat16*)(ws + 8396800);          // 26 KB
    __hip_bfloat16* mw1b = (__hip_bfloat16*)(ws + 8423424);          // 64 KB (permuted)
    __hip_bfloat16* mw2b = (__hip_bfloat16*)(ws + 8488960);          // 64 KB

    dim3 block(256);
    hipLaunchKernelGGL(k0_cvt, dim3(128), block, 0, stream,
                       conv1_w, conv2_w, pw1_w, pw2_w, w1b, w2b, mw1b, mw2b);
    hipLaunchKernelGGL(k2_fused, dim3(Bn * Hs), block, 0, stream,
                       x, w1b, conv1_b, bn_g, bn_b, bn_mean, bn_var,
                       w2b, conv2_b, ln_g, ln_b, y_ln);
    hipLaunchKernelGGL(k3_mlp_mfma, dim3(Bn * Hs), block, 0, stream,
                       y_ln, x, mw1b, pw1_b, mw2b, pw2_b, out);
}

// Round 9
// 108.777 us; speedup vs baseline: 3.8451x; 1.0589x over previous
//
#include <hip/hip_runtime.h>
#include <hip/hip_bf16.h>
#include <math.h>

#define Bn   8
#define DIM  128
#define Hs   64
#define Ws   64
#define PADn 3
#define GC   16
#define Gn   8
#define CMID 32    // DIM/RED
#define NW   392   // K*K*G
#define NWP  416   // w2b padded rows

typedef __bf16 bf16x8 __attribute__((ext_vector_type(8)));
typedef float  f32x4  __attribute__((ext_vector_type(4)));
typedef _Float16 h2v  __attribute__((ext_vector_type(2)));

__device__ __forceinline__ f32x4 mfma16(bf16x8 a, bf16x8 b, f32x4 c) {
    return __builtin_amdgcn_mfma_f32_16x16x32_bf16(a, b, c, 0, 0, 0);
}

__device__ __forceinline__ __bf16 tobf(float v) {
    __hip_bfloat16 h = __float2bfloat16(v);
    return *reinterpret_cast<__bf16*>(&h);
}

__device__ __forceinline__ unsigned su16(float f) {
    __hip_bfloat16 h = __float2bfloat16(f);
    return (unsigned)*reinterpret_cast<unsigned short*>(&h);
}

// ---------------- K0: convert weights to bf16 ----------------
__global__ __launch_bounds__(256) void k0_cvt(const float* __restrict__ w1,
        const float* __restrict__ w2,
        const float* __restrict__ pw1, const float* __restrict__ pw2,
        __hip_bfloat16* __restrict__ w1b, __hip_bfloat16* __restrict__ w2b,
        __hip_bfloat16* __restrict__ mw1b, __hip_bfloat16* __restrict__ mw2b) {
    int i = blockIdx.x * 256 + threadIdx.x;   // 32768 threads
    if (i < CMID * DIM) w1b[i] = __float2bfloat16(w1[i]);
    if (i < NWP * CMID)
        w2b[i] = (i < NW * CMID) ? __float2bfloat16(w2[i]) : __float2bfloat16(0.f);
    mw1b[i] = __float2bfloat16(pw1[i]);
    mw2b[i] = __float2bfloat16(pw2[i]);
}

// ---- K_ALL: conv1+conv2 MFMA, involution, LN, MLP MFMA, residual — one kernel ----
// 512 threads (8 waves). LDS union: phaseA {xp2 dbuf, wgt2, tsh} / phaseB {zsh, y_lds}.
__global__ __launch_bounds__(512) void k_all(const float* __restrict__ x,
        const __hip_bfloat16* __restrict__ w1b, const float* __restrict__ b1v,
        const float* __restrict__ bng, const float* __restrict__ bnb,
        const float* __restrict__ bnm, const float* __restrict__ bnv,
        const __hip_bfloat16* __restrict__ w2b, const float* __restrict__ b2v,
        const float* __restrict__ lng, const float* __restrict__ lnb,
        const __hip_bfloat16* __restrict__ mw1b, const float* __restrict__ mb1,
        const __hip_bfloat16* __restrict__ mw2b, const float* __restrict__ mb2,
        float* __restrict__ out) {
    __shared__ __align__(16) char uni[51200];
    __shared__ float ps[8][64], pss[8][64];
    __shared__ float mu_s[64], rs_s[64];
    // phase A views
    h2v* xp2  = (h2v*)uni;                                   // [2][8][7][72]  32256 B
    h2v* wgt2 = (h2v*)(uni + 32256);                         // [49][66]       12936 B (pad->12944)
    __hip_bfloat16* tsh = (__hip_bfloat16*)(uni + 45200);    // [64][32]       4096 B
    // phase B views (A dead before these are written)
    __hip_bfloat16* zsh  = (__hip_bfloat16*)uni;             // [64][264]      33792 B
    __hip_bfloat16* ylds = (__hip_bfloat16*)(uni + 33792);   // [64][136]      17408 B

    int b = blockIdx.x & 7, h = blockIdx.x >> 3;   // XCD-aware: batch b -> XCD b
    int tid = threadIdx.x, lane = tid & 63, wid = tid >> 6;
    int l15 = lane & 15, l4 = lane >> 4;
    int m = wid & 3, np = wid >> 2;     // m-tile 0..3, n-part 0..1
    int m0 = m * 16;

    // batched stage of group g's patch (pairs cc, cc+8) into xp2[buf]
    auto stage = [&](int g, int buf) {
        const float* xg = x + ((size_t)b * DIM + g * GC) * (Hs * Ws);
        h2v* xb = xp2 + buf * 4032;
        float v0[8], v1[8];
#pragma unroll
        for (int e = 0; e < 8; ++e) {
            int i = tid + e * 512;
            int ccp = i / 490;
            int rem = i - ccp * 490;
            int r = rem / 70, col = rem - r * 70;
            int hh = h + r - PADn, wc = col - PADn;
            bool ok = (i < 3920) & ((unsigned)hh < (unsigned)Hs) &
                      ((unsigned)wc < (unsigned)Ws);
            int off = ok ? ((ccp * Hs + hh) * Ws + wc) : 0;
            v0[e] = ok ? xg[off] : 0.f;
            v1[e] = ok ? xg[off + 8 * Hs * Ws] : 0.f;
        }
#pragma unroll
        for (int e = 0; e < 8; ++e) {
            int i = tid + e * 512;
            if (i < 3920) {
                int ccp = i / 490;
                int rem = i - ccp * 490;
                int r = rem / 70, col = rem - r * 70;
                xb[ccp * 504 + r * 72 + col] = (h2v){(_Float16)v0[e], (_Float16)v1[e]};
            }
        }
    };

    // ---- conv1 via MFMA: wave (m, np) -> pixels m0..m0+15, channels np*16.. ----
    bf16x8 afr[4];
#pragma unroll
    for (int ks = 0; ks < 4; ++ks)
#pragma unroll
        for (int i = 0; i < 8; ++i) {
            int c = ks * 32 + l4 * 8 + i;
            afr[ks][i] = tobf(x[(((size_t)b * DIM + c) * Hs + h) * Ws + m0 + l15]);
        }

    stage(0, 0);

    f32x4 acc1 = (f32x4){0.f, 0.f, 0.f, 0.f};
#pragma unroll
    for (int ks = 0; ks < 4; ++ks) {
        bf16x8 bf = *(const bf16x8*)&w1b[(np * 16 + l15) * DIM + ks * 32 + l4 * 8];
        acc1 = mfma16(afr[ks], bf, acc1);
    }
    {
        int o = np * 16 + l15;
        float sc = bng[o] * rsqrtf(bnv[o] + 1e-5f);
        float sh = bnb[o] - bnm[o] * sc;
        float bv = b1v[o];
#pragma unroll
        for (int r = 0; r < 4; ++r) {
            float v = (acc1[r] + bv) * sc + sh;
            tsh[(m0 + l4 * 4 + r) * CMID + o] = __float2bfloat16(fmaxf(v, 0.f));
        }
    }
    __syncthreads();   // tsh ready; stage(0) done

    bf16x8 a_t = *(const bf16x8*)&tsh[(m0 + l15) * CMID + l4 * 8];

    unsigned ypk[8];           // packed bf16 y: word g = channels (g*16+wid, g*16+wid+8)
    float s = 0.f, ss = 0.f;

    // ROLLED group loop (full unroll -> VGPR explosion, R5/R6 lesson)
#pragma unroll 1
    for (int g = 0; g < Gn; ++g) {
        int buf = g & 1;
        // ---- conv2 via MFMA: wave (m,np) does n-tiles np*2, np*2+1 ----
        f32x4 ac[2];
        ac[0] = (f32x4){0.f, 0.f, 0.f, 0.f};
        ac[1] = (f32x4){0.f, 0.f, 0.f, 0.f};
#pragma unroll
        for (int j = 0; j < 2; ++j) {
            bf16x8 bf = *(const bf16x8*)&w2b[(size_t)(g * 49 + (np * 2 + j) * 16 + l15) * CMID + l4 * 8];
            ac[j] = mfma16(a_t, bf, ac[j]);
        }
#pragma unroll
        for (int j = 0; j < 2; ++j) {
            int p = (np * 2 + j) * 16 + l15;
            if (p < 49) {
                float bias = b2v[g * 49 + p];
#pragma unroll
                for (int r = 0; r < 4; ++r) {
                    _Float16 hf16 = (_Float16)(ac[j][r] + bias);
                    wgt2[p * 66 + m0 + l4 * 4 + r] = (h2v){hf16, hf16};
                }
            }
        }
        __syncthreads();   // wgt2 ready; xp2[buf] staged

        if (g < Gn - 1) stage(g + 1, buf ^ 1);

        h2v wv[49];
#pragma unroll
        for (int p = 0; p < 49; ++p) wv[p] = wgt2[p * 66 + lane];

        // involution: wave wid owns channel pair (g*16+wid, +8), pixel = lane
        const h2v* xrow = xp2 + buf * 4032 + wid * 504;
        float ax = 0.f, ay = 0.f;
#pragma unroll
        for (int r = 0; r < 7; ++r) {
            h2v hacc = (h2v){(_Float16)0.f, (_Float16)0.f};
#pragma unroll
            for (int j = 0; j < 7; ++j)
                hacc = wv[r * 7 + j] * xrow[r * 72 + lane + j] + hacc;
            ax += (float)hacc.x;
            ay += (float)hacc.y;
        }
        ypk[g] = su16(ax) | (su16(ay) << 16);
        s += ax + ay;
        ss = fmaf(ax, ax, fmaf(ay, ay, ss));
        __syncthreads();   // staging visible block-wide; wgt2/xp2[buf] free
    }

    // ---- LayerNorm ----
    ps[wid][lane] = s; pss[wid][lane] = ss;
    __syncthreads();
    if (tid < 64) {
        float sa = 0.f, sb = 0.f;
#pragma unroll
        for (int k = 0; k < 8; ++k) { sa += ps[k][tid]; sb += pss[k][tid]; }
        float mu = sa * (1.f / DIM);
        float var = sb * (1.f / DIM) - mu * mu;
        mu_s[tid] = mu;
        rs_s[tid] = rsqrtf(var + 1e-6f);
    }
    __syncthreads();
    {
        float mu = mu_s[lane], rs = rs_s[lane];
#pragma unroll
        for (int g = 0; g < 8; ++g) {
            unsigned wk = ypk[g];
            float lo = __uint_as_float(wk << 16);
            float hi = __uint_as_float(wk & 0xffff0000u);
            int c0 = g * 16 + wid, c1 = c0 + 8;
            lo = (lo - mu) * rs * lng[c0] + lnb[c0];
            hi = (hi - mu) * rs * lng[c1] + lnb[c1];
            ylds[lane * 136 + c0] = __float2bfloat16(lo);
            ylds[lane * 136 + c1] = __float2bfloat16(hi);
        }
    }
    __syncthreads();   // ylds ready (overwrote wgt2/tsh region — both dead)

    // ---- MLP GEMM1: z[64][256], wave (m,np) does n-tiles np*8..np*8+7 ----
    bf16x8 ay[4];
#pragma unroll
    for (int ks = 0; ks < 4; ++ks)
        ay[ks] = *(const bf16x8*)&ylds[(m0 + l15) * 136 + ks * 32 + l4 * 8];

    f32x4 zac[8];
#pragma unroll
    for (int j = 0; j < 8; ++j) zac[j] = (f32x4){0.f, 0.f, 0.f, 0.f};
#pragma unroll
    for (int ks = 0; ks < 4; ++ks)
#pragma unroll
        for (int j = 0; j < 8; ++j) {
            bf16x8 bf = *(const bf16x8*)&mw1b[((np * 8 + j) * 16 + l15) * DIM + ks * 32 + l4 * 8];
            zac[j] = mfma16(ay[ks], bf, zac[j]);
        }
#pragma unroll
    for (int j = 0; j < 8; ++j) {
        float bv = mb1[(np * 8 + j) * 16 + l15];
#pragma unroll
        for (int r = 0; r < 4; ++r) {
            float v = zac[j][r] + bv;
            v = v * 0.5f * (1.f + erff(v * 0.70710678118f));
            zsh[(m0 + l4 * 4 + r) * 264 + (np * 8 + j) * 16 + l15] = __float2bfloat16(v);
        }
    }
    __syncthreads();   // zsh ready (overwrote xp2 region — dead)

    // ---- MLP GEMM2: out[64][128], wave (m,np) does n-tiles np*4..np*4+3 ----
    bf16x8 az[8];
#pragma unroll
    for (int ks = 0; ks < 8; ++ks)
        az[ks] = *(const bf16x8*)&zsh[(m0 + l15) * 264 + ks * 32 + l4 * 8];

    f32x4 oac[4];
#pragma unroll
    for (int j = 0; j < 4; ++j) oac[j] = (f32x4){0.f, 0.f, 0.f, 0.f};
#pragma unroll
    for (int ks = 0; ks < 8; ++ks)
#pragma unroll
        for (int j = 0; j < 4; ++j) {
            bf16x8 bf = *(const bf16x8*)&mw2b[((np * 4 + j) * 16 + l15) * 256 + ks * 32 + l4 * 8];
            oac[j] = mfma16(az[ks], bf, oac[j]);
        }

    // residual + store (batched float4 loads, then float4 stores)
    float4 xr[4];
#pragma unroll
    for (int j = 0; j < 4; ++j) {
        int c = (np * 4 + j) * 16 + l15;
        xr[j] = *(const float4*)&x[(((size_t)b * DIM + c) * Hs + h) * Ws + m0 + l4 * 4];
    }
#pragma unroll
    for (int j = 0; j < 4; ++j) {
        int c = (np * 4 + j) * 16 + l15;
        float bv = mb2[c];
        size_t gi = (((size_t)b * DIM + c) * Hs + h) * Ws + m0 + l4 * 4;
        float4 o;
        o.x = oac[j][0] + bv + xr[j].x;
        o.y = oac[j][1] + bv + xr[j].y;
        o.z = oac[j][2] + bv + xr[j].z;
        o.w = oac[j][3] + bv + xr[j].w;
        *(float4*)&out[gi] = o;
    }
}

extern "C" void kernel_launch(void* const* d_in, const int* in_sizes, int n_in,
                              void* d_out, int out_size, void* d_ws, size_t ws_size,
                              hipStream_t stream) {
    const float* x       = (const float*)d_in[0];
    const float* conv1_w = (const float*)d_in[1];
    const float* conv1_b = (const float*)d_in[2];
    const float* bn_g    = (const float*)d_in[3];
    const float* bn_b    = (const float*)d_in[4];
    const float* bn_mean = (const float*)d_in[5];
    const float* bn_var  = (const float*)d_in[6];
    const float* conv2_w = (const float*)d_in[7];
    const float* conv2_b = (const float*)d_in[8];
    const float* ln_g    = (const float*)d_in[9];
    const float* ln_b    = (const float*)d_in[10];
    const float* pw1_w   = (const float*)d_in[11];
    const float* pw1_b   = (const float*)d_in[12];
    const float* pw2_w   = (const float*)d_in[13];
    const float* pw2_b   = (const float*)d_in[14];
    float* out = (float*)d_out;

    char* ws = (char*)d_ws;
    __hip_bfloat16* w1b  = (__hip_bfloat16*)ws;              // 8 KB
    __hip_bfloat16* w2b  = (__hip_bfloat16*)(ws + 8192);     // 26 KB
    __hip_bfloat16* mw1b = (__hip_bfloat16*)(ws + 34816);    // 64 KB
    __hip_bfloat16* mw2b = (__hip_bfloat16*)(ws + 100352);   // 64 KB

    hipLaunchKernelGGL(k0_cvt, dim3(128), dim3(256), 0, stream,
                       conv1_w, conv2_w, pw1_w, pw2_w, w1b, w2b, mw1b, mw2b);
    hipLaunchKernelGGL(k_all, dim3(Bn * Hs), dim3(512), 0, stream,
                       x, w1b, conv1_b, bn_g, bn_b, bn_mean, bn_var,
                       w2b, conv2_b, ln_g, ln_b,
                       mw1b, pw1_b, mw2b, pw2_b, out);
}

// Round 11
// 95.339 us; speedup vs baseline: 4.3871x; 1.1409x over previous
//
#include <hip/hip_runtime.h>
#include <hip/hip_bf16.h>
#include <math.h>

#define Bn   8
#define DIM  128
#define Hs   64
#define Ws   64
#define PADn 3
#define GC   16
#define Gn   8
#define CMID 32    // DIM/RED
#define NW   392   // K*K*G
#define NWP  416   // w2b padded rows

typedef __bf16 bf16x8 __attribute__((ext_vector_type(8)));
typedef float  f32x4  __attribute__((ext_vector_type(4)));
typedef _Float16 h2v  __attribute__((ext_vector_type(2)));
typedef __fp16   fp16x2 __attribute__((ext_vector_type(2)));

__device__ __forceinline__ f32x4 mfma16(bf16x8 a, bf16x8 b, f32x4 c) {
    return __builtin_amdgcn_mfma_f32_16x16x32_bf16(a, b, c, 0, 0, 0);
}

__device__ __forceinline__ __bf16 tobf(float v) {
    __hip_bfloat16 h = __float2bfloat16(v);
    return *reinterpret_cast<__bf16*>(&h);
}

__device__ __forceinline__ unsigned su16(float f) {
    __hip_bfloat16 h = __float2bfloat16(f);
    return (unsigned)*reinterpret_cast<unsigned short*>(&h);
}

__device__ __forceinline__ h2v pk2h(float a, float b) {
    fp16x2 p = __builtin_amdgcn_cvt_pkrtz(a, b);
    return __builtin_bit_cast(h2v, p);
}

// tanh-form gelu: v * t/(t+1), t = exp2(2*log2e*u), u = 0.79788456*v*(1+0.044715 v^2)
__device__ __forceinline__ float gelu_t(float v) {
    float u = 0.7978845608f * v * fmaf(0.044715f, v * v, 1.0f);
    float t = __builtin_amdgcn_exp2f(fminf(u, 30.f) * 2.885390082f);
    return v * t * __builtin_amdgcn_rcpf(t + 1.0f);
}

// ---------------- K0: convert weights to bf16 ----------------
__global__ __launch_bounds__(256) void k0_cvt(const float* __restrict__ w1,
        const float* __restrict__ w2,
        const float* __restrict__ pw1, const float* __restrict__ pw2,
        __hip_bfloat16* __restrict__ w1b, __hip_bfloat16* __restrict__ w2b,
        __hip_bfloat16* __restrict__ mw1b, __hip_bfloat16* __restrict__ mw2b) {
    int i = blockIdx.x * 256 + threadIdx.x;   // 32768 threads
    if (i < CMID * DIM) w1b[i] = __float2bfloat16(w1[i]);
    if (i < NWP * CMID)
        w2b[i] = (i < NW * CMID) ? __float2bfloat16(w2[i]) : __float2bfloat16(0.f);
    mw1b[i] = __float2bfloat16(pw1[i]);
    mw2b[i] = __float2bfloat16(pw2[i]);
}

// ---- K_ALL: conv1+conv2 MFMA, involution, LN, MLP MFMA, residual ----
// 512 threads (8 waves). LDS union phases: A{xp2,wgt2,tsh} / LN{ps,pss,mu,rs} / B{zsh,ylds}.
__global__ __launch_bounds__(512) void k_all(const float* __restrict__ x,
        const __hip_bfloat16* __restrict__ w1b, const float* __restrict__ b1v,
        const float* __restrict__ bng, const float* __restrict__ bnb,
        const float* __restrict__ bnm, const float* __restrict__ bnv,
        const __hip_bfloat16* __restrict__ w2b, const float* __restrict__ b2v,
        const float* __restrict__ lng, const float* __restrict__ lnb,
        const __hip_bfloat16* __restrict__ mw1b, const float* __restrict__ mb1,
        const __hip_bfloat16* __restrict__ mw2b, const float* __restrict__ mb2,
        float* __restrict__ out) {
    __shared__ __align__(16) char uni[51200];
    // phase A
    h2v* xp2  = (h2v*)uni;                                   // [2][8][7][72]  32256 B
    h2v* wgt2 = (h2v*)(uni + 32256);                         // [49][66]       12936 B
    __hip_bfloat16* tsh = (__hip_bfloat16*)(uni + 45200);    // [64][32]       4096 B
    // phase LN (xp2 region, dead)
    float* ps   = (float*)uni;                               // [8][64] 2048 B
    float* pss  = (float*)(uni + 2048);                      // 2048 B
    float* mu_s = (float*)(uni + 4096);                      // 256 B
    float* rs_s = (float*)(uni + 4352);                      // 256 B
    // phase B
    __hip_bfloat16* zsh  = (__hip_bfloat16*)uni;             // [64][264] XOR-swz  33792 B
    __hip_bfloat16* ylds = (__hip_bfloat16*)(uni + 33792);   // [64][136] XOR-swz  17408 B

    int b = blockIdx.x & 7, h = blockIdx.x >> 3;   // XCD-aware: batch b -> XCD b
    int tid = threadIdx.x, lane = tid & 63, wid = tid >> 6;
    int l15 = lane & 15, l4 = lane >> 4;
    int m = wid & 3, np = wid >> 2;
    int m0 = m * 16;

    // ---- stage geometry hoisted (g-invariant): 3920 = 8 x 490 elems, 8 iters x 512 ----
    int goff[8], ldso[8];
    unsigned smask = 0;
#pragma unroll
    for (int e = 0; e < 8; ++e) {
        int i = tid + e * 512;
        int ccp = i / 490;
        int rem = i - ccp * 490;
        int r = rem / 70, col = rem - r * 70;
        int hh = h + r - PADn, wc = col - PADn;
        bool ok = (i < 3920) & ((unsigned)hh < (unsigned)Hs) & ((unsigned)wc < (unsigned)Ws);
        smask |= (unsigned)ok << e;
        goff[e] = (ccp * Hs + hh) * Ws + wc;
        ldso[e] = ccp * 504 + r * 72 + col;
    }

    auto stage = [&](int g, int buf) {
        const float* xg = x + ((size_t)b * DIM + g * GC) * (Hs * Ws);
        h2v* xb = xp2 + buf * 4032;
        float v0[8], v1[8];
#pragma unroll
        for (int e = 0; e < 8; ++e) {
            bool ok = (smask >> e) & 1u;
            v0[e] = ok ? xg[goff[e]] : 0.f;
            v1[e] = ok ? xg[goff[e] + 8 * Hs * Ws] : 0.f;
        }
#pragma unroll
        for (int e = 0; e < 8; ++e) {
            if (e < 7 || tid < 336) {    // i < 3920
                xb[ldso[e]] = pk2h(v0[e], v1[e]);
            }
        }
    };

    // ---- conv1 via MFMA ----
    bf16x8 afr[4];
#pragma unroll
    for (int ks = 0; ks < 4; ++ks)
#pragma unroll
        for (int i = 0; i < 8; ++i) {
            int c = ks * 32 + l4 * 8 + i;
            afr[ks][i] = tobf(x[(((size_t)b * DIM + c) * Hs + h) * Ws + m0 + l15]);
        }

    stage(0, 0);

    f32x4 acc1 = (f32x4){0.f, 0.f, 0.f, 0.f};
#pragma unroll
    for (int ks = 0; ks < 4; ++ks) {
        bf16x8 bf = *(const bf16x8*)&w1b[(np * 16 + l15) * DIM + ks * 32 + l4 * 8];
        acc1 = mfma16(afr[ks], bf, acc1);
    }
    {
        int o = np * 16 + l15;
        float sc = bng[o] * rsqrtf(bnv[o] + 1e-5f);
        float sh = bnb[o] - bnm[o] * sc;
        float bv = b1v[o];
#pragma unroll
        for (int r = 0; r < 4; ++r) {
            float v = (acc1[r] + bv) * sc + sh;
            tsh[(m0 + l4 * 4 + r) * CMID + o] = __float2bfloat16(fmaxf(v, 0.f));
        }
    }
    __syncthreads();   // tsh ready; stage(0) done

    bf16x8 a_t = *(const bf16x8*)&tsh[(m0 + l15) * CMID + l4 * 8];

    unsigned ypk[8];           // packed bf16 y: word g = channels (g*16+wid, +8)
    float s = 0.f, ss = 0.f;

#pragma unroll 1
    for (int g = 0; g < Gn; ++g) {
        int buf = g & 1;
        f32x4 ac[2];
        ac[0] = (f32x4){0.f, 0.f, 0.f, 0.f};
        ac[1] = (f32x4){0.f, 0.f, 0.f, 0.f};
#pragma unroll
        for (int j = 0; j < 2; ++j) {
            bf16x8 bf = *(const bf16x8*)&w2b[(size_t)(g * 49 + (np * 2 + j) * 16 + l15) * CMID + l4 * 8];
            ac[j] = mfma16(a_t, bf, ac[j]);
        }
#pragma unroll
        for (int j = 0; j < 2; ++j) {
            int p = (np * 2 + j) * 16 + l15;
            if (p < 49) {
                float bias = b2v[g * 49 + p];
#pragma unroll
                for (int r = 0; r < 4; ++r) {
                    _Float16 hf16 = (_Float16)(ac[j][r] + bias);
                    wgt2[p * 66 + m0 + l4 * 4 + r] = (h2v){hf16, hf16};
                }
            }
        }
        __syncthreads();   // wgt2 ready; xp2[buf] staged

        if (g < Gn - 1) stage(g + 1, buf ^ 1);

        h2v wv[49];
#pragma unroll
        for (int p = 0; p < 49; ++p) wv[p] = wgt2[p * 66 + lane];

        const h2v* xrow = xp2 + buf * 4032 + wid * 504;
        float ax = 0.f, ay = 0.f;
#pragma unroll
        for (int r = 0; r < 7; ++r) {
            h2v hacc = (h2v){(_Float16)0.f, (_Float16)0.f};
#pragma unroll
            for (int j = 0; j < 7; ++j)
                hacc = wv[r * 7 + j] * xrow[r * 72 + lane + j] + hacc;
            ax += (float)hacc.x;
            ay += (float)hacc.y;
        }
        ypk[g] = su16(ax) | (su16(ay) << 16);
        s += ax + ay;
        ss = fmaf(ax, ax, fmaf(ay, ay, ss));
        __syncthreads();   // staging visible; wgt2/xp2[buf] free
    }

    // ---- LayerNorm (partials into xp2 region — dead) ----
    ps[wid * 64 + lane] = s; pss[wid * 64 + lane] = ss;
    __syncthreads();
    if (tid < 64) {
        float sa = 0.f, sb = 0.f;
#pragma unroll
        for (int k = 0; k < 8; ++k) { sa += ps[k * 64 + tid]; sb += pss[k * 64 + tid]; }
        float mu = sa * (1.f / DIM);
        float var = sb * (1.f / DIM) - mu * mu;
        mu_s[tid] = mu;
        rs_s[tid] = rsqrtf(var + 1e-6f);
    }
    __syncthreads();
    {
        float mu = mu_s[lane], rs = rs_s[lane];
        int rsw = lane & 7;                       // row XOR key
#pragma unroll
        for (int g = 0; g < 8; ++g) {
            unsigned wk = ypk[g];
            float lo = __uint_as_float(wk << 16);
            float hi = __uint_as_float(wk & 0xffff0000u);
            int c0 = g * 16 + wid, c1 = c0 + 8;
            lo = (lo - mu) * rs * lng[c0] + lnb[c0];
            hi = (hi - mu) * rs * lng[c1] + lnb[c1];
            ylds[lane * 136 + (((2 * g)     ^ rsw) << 3) + wid] = __float2bfloat16(lo);
            ylds[lane * 136 + (((2 * g + 1) ^ rsw) << 3) + wid] = __float2bfloat16(hi);
        }
    }
    __syncthreads();   // ylds ready (overwrote wgt2/tsh — dead)

    // ---- MLP GEMM1: z[64][256] ----
    int rk = l15 & 7;                             // read-row XOR key
    bf16x8 ay[4];
#pragma unroll
    for (int ks = 0; ks < 4; ++ks)
        ay[ks] = *(const bf16x8*)&ylds[(m0 + l15) * 136 + (((ks * 4 + l4) ^ rk) << 3)];

    f32x4 zac[8];
#pragma unroll
    for (int j = 0; j < 8; ++j) zac[j] = (f32x4){0.f, 0.f, 0.f, 0.f};
#pragma unroll
    for (int ks = 0; ks < 4; ++ks)
#pragma unroll
        for (int j = 0; j < 8; ++j) {
            bf16x8 bf = *(const bf16x8*)&mw1b[((np * 8 + j) * 16 + l15) * DIM + ks * 32 + l4 * 8];
            zac[j] = mfma16(ay[ks], bf, zac[j]);
        }
#pragma unroll
    for (int j = 0; j < 8; ++j) {
        float bv = mb1[(np * 8 + j) * 16 + l15];
        int Bw = (np * 8 + j) * 2 + (l15 >> 3);
#pragma unroll
        for (int r = 0; r < 4; ++r) {
            float v = gelu_t(zac[j][r] + bv);
            int row = m0 + l4 * 4 + r;
            zsh[row * 264 + ((Bw ^ (row & 7)) << 3) + (l15 & 7)] = __float2bfloat16(v);
        }
    }
    __syncthreads();   // zsh ready (overwrote xp2/ps/mu — dead)

    // ---- MLP GEMM2: out[64][128] ----
    bf16x8 az[8];
#pragma unroll
    for (int ks = 0; ks < 8; ++ks)
        az[ks] = *(const bf16x8*)&zsh[(m0 + l15) * 264 + (((ks * 4 + l4) ^ rk) << 3)];

    f32x4 oac[4];
#pragma unroll
    for (int j = 0; j < 4; ++j) oac[j] = (f32x4){0.f, 0.f, 0.f, 0.f};
#pragma unroll
    for (int ks = 0; ks < 8; ++ks)
#pragma unroll
        for (int j = 0; j < 4; ++j) {
            bf16x8 bf = *(const bf16x8*)&mw2b[((np * 4 + j) * 16 + l15) * 256 + ks * 32 + l4 * 8];
            oac[j] = mfma16(az[ks], bf, oac[j]);
        }

    float4 xr[4];
#pragma unroll
    for (int j = 0; j < 4; ++j) {
        int c = (np * 4 + j) * 16 + l15;
        xr[j] = *(const float4*)&x[(((size_t)b * DIM + c) * Hs + h) * Ws + m0 + l4 * 4];
    }
#pragma unroll
    for (int j = 0; j < 4; ++j) {
        int c = (np * 4 + j) * 16 + l15;
        float bv = mb2[c];
        size_t gi = (((size_t)b * DIM + c) * Hs + h) * Ws + m0 + l4 * 4;
        float4 o;
        o.x = oac[j][0] + bv + xr[j].x;
        o.y = oac[j][1] + bv + xr[j].y;
        o.z = oac[j][2] + bv + xr[j].z;
        o.w = oac[j][3] + bv + xr[j].w;
        *(float4*)&out[gi] = o;
    }
}

extern "C" void kernel_launch(void* const* d_in, const int* in_sizes, int n_in,
                              void* d_out, int out_size, void* d_ws, size_t ws_size,
                              hipStream_t stream) {
    const float* x       = (const float*)d_in[0];
    const float* conv1_w = (const float*)d_in[1];
    const float* conv1_b = (const float*)d_in[2];
    const float* bn_g    = (const float*)d_in[3];
    const float* bn_b    = (const float*)d_in[4];
    const float* bn_mean = (const float*)d_in[5];
    const float* bn_var  = (const float*)d_in[6];
    const float* conv2_w = (const float*)d_in[7];
    const float* conv2_b = (const float*)d_in[8];
    const float* ln_g    = (const float*)d_in[9];
    const float* ln_b    = (const float*)d_in[10];
    const float* pw1_w   = (const float*)d_in[11];
    const float* pw1_b   = (const float*)d_in[12];
    const float* pw2_w   = (const float*)d_in[13];
    const float* pw2_b   = (const float*)d_in[14];
    float* out = (float*)d_out;

    char* ws = (char*)d_ws;
    __hip_bfloat16* w1b  = (__hip_bfloat16*)ws;              // 8 KB
    __hip_bfloat16* w2b  = (__hip_bfloat16*)(ws + 8192);     // 26 KB
    __hip_bfloat16* mw1b = (__hip_bfloat16*)(ws + 34816);    // 64 KB
    __hip_bfloat16* mw2b = (__hip_bfloat16*)(ws + 100352);   // 64 KB

    hipLaunchKernelGGL(k0_cvt, dim3(128), dim3(256), 0, stream,
                       conv1_w, conv2_w, pw1_w, pw2_w, w1b, w2b, mw1b, mw2b);
    hipLaunchKernelGGL(k_all, dim3(Bn * Hs), dim3(512), 0, stream,
                       x, w1b, conv1_b, bn_g, bn_b, bn_mean, bn_var,
                       w2b, conv2_b, ln_g, ln_b,
                       mw1b, pw1_b, mw2b, pw2_b, out);
}